// Round 10
// baseline (391.115 us; speedup 1.0000x reference)
//
#include <hip/hip_runtime.h>
#include <hip/hip_bf16.h>

// Problem constants
#define T_TOK 2048
#define HID   1024
#define FF    3584
#define NE    8
#define TOPK  2
#define GRIDY1 24         // >= max tiles at BM=256: 16 + 7
#define GRIDY2 40         // >= max tiles at BM=128: 32 + 7

typedef __bf16 bf16x8 __attribute__((ext_vector_type(8)));
typedef float  f32x4  __attribute__((ext_vector_type(4)));
typedef unsigned short u16x8 __attribute__((ext_vector_type(8)));

// ---- workspace layout (bytes) ----
#define WS_COUNTS   0u
#define WS_OFFSETS  64u
#define WS_TILECNT  128u
#define WS_TLE1     256u
#define WS_TLM1     512u
#define WS_TLE2     768u
#define WS_TLM2     1024u
#define WS_TOPKI    4096u
#define WS_TOPKW    20480u
#define WS_SLOTPOS  36864u
#define WS_SLOTROW  53248u
#define WS_ROUTETOK 69632u
#define WS_XG       131072u                           // ushort[4096*1024] (8 MB), swizzled
#define WS_ACT      (WS_XG + 4096u*1024u*2u)          // ushort[4096*3584] (29.4 MB), swizzled
#define WS_Y        (WS_ACT + 4096u*3584u*2u)         // float[ks*4096*1024]
#define Y_STRIDE    (4096u*1024u)

static __device__ __forceinline__ unsigned short f2bf(float f) {
    unsigned int u = __builtin_bit_cast(unsigned int, f);
    u += 0x7FFFu + ((u >> 16) & 1u);
    return (unsigned short)(u >> 16);
}
static __device__ __forceinline__ unsigned int cvtpk(float lo, float hi) {
    unsigned int r;
    asm("v_cvt_pk_bf16_f32 %0, %1, %2" : "=v"(r) : "v"(lo), "v"(hi));
    return r;
}

// ---------------- router ----------------
__global__ __launch_bounds__(256) void k_router(
    const float* __restrict__ x, const float* __restrict__ gw,
    int* __restrict__ counts, int* __restrict__ topki,
    float* __restrict__ topkw, int* __restrict__ slotpos)
{
    int t = blockIdx.x * 4 + (threadIdx.x >> 6);
    int l = threadIdx.x & 63;
    const float* xr = x + (size_t)t * HID;
    float acc[NE];
#pragma unroll
    for (int e = 0; e < NE; ++e) acc[e] = 0.f;
#pragma unroll
    for (int i = 0; i < 4; ++i) {
        int h = l * 4 + i * 256;
        float4 xv = *(const float4*)(xr + h);
#pragma unroll
        for (int e = 0; e < NE; ++e) {
            float4 g = *(const float4*)(gw + e * HID + h);
            acc[e] += xv.x * g.x + xv.y * g.y + xv.z * g.z + xv.w * g.w;
        }
    }
#pragma unroll
    for (int e = 0; e < NE; ++e) {
#pragma unroll
        for (int off = 32; off; off >>= 1) acc[e] += __shfl_xor(acc[e], off);
    }
    if (l == 0) {
        float best = -1e30f, second = -1e30f;
        int bi = 0, si = 0;
#pragma unroll
        for (int e = 0; e < NE; ++e) {
            float v = acc[e];
            if (v > best) { second = best; si = bi; best = v; bi = e; }
            else if (v > second) { second = v; si = e; }
        }
        float w0 = 1.f / (1.f + __expf(second - best));
        float w1 = 1.f - w0;
        topki[2 * t] = bi;  topki[2 * t + 1] = si;
        topkw[2 * t] = w0;  topkw[2 * t + 1] = w1;
        slotpos[2 * t]     = atomicAdd(&counts[bi], 1);
        slotpos[2 * t + 1] = atomicAdd(&counts[si], 1);
    }
}

// ---------------- prefix + two tile lists (BM=256 for gemm1, BM=128 for gemm2) ----------------
__global__ void k_prefix(const int* __restrict__ counts, int* __restrict__ offsets,
                         int* __restrict__ tl1e, int* __restrict__ tl1m,
                         int* __restrict__ tl2e, int* __restrict__ tl2m,
                         int* __restrict__ tilecnt) {
    if (threadIdx.x == 0) {
        int o = 0;
#pragma unroll
        for (int e = 0; e < NE; ++e) { offsets[e] = o; o += counts[e]; }
        int n1 = 0, n2 = 0;
        for (int e = 0; e < NE; ++e) {
            int t1 = (counts[e] + 255) >> 8;
            for (int i = 0; i < t1; ++i) { tl1e[n1] = e; tl1m[n1] = i; ++n1; }
            int t2 = (counts[e] + 127) >> 7;
            for (int i = 0; i < t2; ++i) { tl2e[n2] = e; tl2m[n2] = i; ++n2; }
        }
        tilecnt[0] = n1; tilecnt[1] = n2;
    }
}

// ---------------- fill routing ----------------
__global__ void k_fill(const int* __restrict__ topki, const int* __restrict__ slotpos,
                       const int* __restrict__ offsets, int* __restrict__ routetok,
                       int* __restrict__ slotrow) {
    int j = blockIdx.x * blockDim.x + threadIdx.x;
    if (j >= T_TOK * TOPK) return;
    int e = topki[j];
    int row = offsets[e] + slotpos[j];
    routetok[row] = j >> 1;
    slotrow[j] = row;
}

// ---------------- gather + convert + swizzle (keyed on global slot row) ----------------
__global__ void k_gather(const float* __restrict__ x, const int* __restrict__ routetok,
                         unsigned short* __restrict__ xg) {
    int j = blockIdx.x * blockDim.x + threadIdx.x;
    int r = j >> 8;
    int c = (j & 255) * 4;
    int tok = routetok[r];
    float4 v = *(const float4*)(x + (size_t)tok * HID + c);
    ushort4 o;
    o.x = f2bf(v.x); o.y = f2bf(v.y); o.z = f2bf(v.z); o.w = f2bf(v.w);
    int sc = c ^ ((r & 7) << 3);
    *(ushort4*)(xg + (size_t)r * HID + sc) = o;
}

// ---------------- GEMM1: act = silu(Xg@w1^T) * (Xg@w3^T) ----------------
// (identical to R9) 512 thr / 8 waves, BM=256, BN=64 (x2), BK=64, stride-64 XOR swizzle.
__global__ __launch_bounds__(512, 4) void k_gemm1(
    const unsigned short* __restrict__ xg, const float* __restrict__ w1,
    const float* __restrict__ w3, const int* __restrict__ counts,
    const int* __restrict__ offsets, const int* __restrict__ tle,
    const int* __restrict__ tlm, const int* __restrict__ tilecnt,
    unsigned short* __restrict__ act)
{
    int by = blockIdx.y;
    if (by >= tilecnt[0]) return;
    int e = tle[by];
    int rbase = tlm[by] * 256;
    int cnt = counts[e], obase = offsets[e];
    int fbase = blockIdx.x * 64;

    __shared__ __align__(16) unsigned short lA[256 * 64];   // 32 KB
    __shared__ __align__(16) unsigned short lB1[64 * 64];   // 8 KB
    __shared__ __align__(16) unsigned short lB3[64 * 64];   // 8 KB

    int tid = threadIdx.x;
    const int ra0 = tid >> 3, ca = (tid & 7) * 8;
    const int rb0 = tid >> 4, cb = (tid & 15) * 4;
    const unsigned short* pa[4];
#pragma unroll
    for (int i = 0; i < 4; ++i) {
        int r = obase + rbase + ra0 + 64 * i;
        if (r > 4095) r = 4095;
        pa[i] = xg + (size_t)r * HID + ca;
    }
    const float* w1e = w1 + ((size_t)e * FF + fbase) * HID;
    const float* w3e = w3 + ((size_t)e * FF + fbase) * HID;
    const float* pb1[2];
    const float* pb3[2];
    int wba[2];
#pragma unroll
    for (int i = 0; i < 2; ++i) {
        int row = rb0 + 32 * i;
        pb1[i] = w1e + (size_t)row * HID + cb;
        pb3[i] = w3e + (size_t)row * HID + cb;
        wba[i] = row * 64 + (cb ^ ((row & 7) << 3));
    }

    int lane = tid & 63, wv = tid >> 6, wr = wv >> 1, wc = wv & 1;
    int klane = (lane >> 4) * 8;
    int swzA = (((obase & 7) + (lane & 7)) & 7) << 3;
    int swzB = (lane & 7) << 3;
    f32x4 accg[4][2], accu[4][2];
#pragma unroll
    for (int m = 0; m < 4; ++m)
#pragma unroll
        for (int n = 0; n < 2; ++n) {
            accg[m][n] = (f32x4){0.f, 0.f, 0.f, 0.f};
            accu[m][n] = (f32x4){0.f, 0.f, 0.f, 0.f};
        }

    u16x8 ra[4]; float4 r1[2], r3[2];
#pragma unroll
    for (int i = 0; i < 4; ++i) ra[i] = *(const u16x8*)(pa[i]);
#pragma unroll
    for (int i = 0; i < 2; ++i) { r1[i] = *(const float4*)(pb1[i]); r3[i] = *(const float4*)(pb3[i]); }

    for (int kt = 0; kt < HID / 64; ++kt) {
#pragma unroll
        for (int i = 0; i < 4; ++i)
            *(u16x8*)(lA + (ra0 + 64 * i) * 64 + ca) = ra[i];
#pragma unroll
        for (int i = 0; i < 2; ++i) {
            uint2 p;
            p.x = cvtpk(r1[i].x, r1[i].y); p.y = cvtpk(r1[i].z, r1[i].w);
            *(uint2*)(lB1 + wba[i]) = p;
            p.x = cvtpk(r3[i].x, r3[i].y); p.y = cvtpk(r3[i].z, r3[i].w);
            *(uint2*)(lB3 + wba[i]) = p;
        }
        __syncthreads();
        if (kt < HID / 64 - 1) {
            int kof = (kt + 1) * 64;
#pragma unroll
            for (int i = 0; i < 4; ++i) ra[i] = *(const u16x8*)(pa[i] + kof);
#pragma unroll
            for (int i = 0; i < 2; ++i) {
                r1[i] = *(const float4*)(pb1[i] + kof);
                r3[i] = *(const float4*)(pb3[i] + kof);
            }
        }
#pragma unroll
        for (int kk = 0; kk < 64; kk += 32) {
            int kc = kk + klane;
            int kA = kc ^ swzA, kB = kc ^ swzB;
            bf16x8 a[4], b1[2], b3[2];
#pragma unroll
            for (int m = 0; m < 4; ++m)
                a[m] = *(const bf16x8*)(lA + (wr * 64 + m * 16 + (lane & 15)) * 64 + kA);
#pragma unroll
            for (int n = 0; n < 2; ++n) {
                b1[n] = *(const bf16x8*)(lB1 + (wc * 32 + n * 16 + (lane & 15)) * 64 + kB);
                b3[n] = *(const bf16x8*)(lB3 + (wc * 32 + n * 16 + (lane & 15)) * 64 + kB);
            }
#pragma unroll
            for (int m = 0; m < 4; ++m)
#pragma unroll
                for (int n = 0; n < 2; ++n) {
                    accg[m][n] = __builtin_amdgcn_mfma_f32_16x16x32_bf16(a[m], b1[n], accg[m][n], 0, 0, 0);
                    accu[m][n] = __builtin_amdgcn_mfma_f32_16x16x32_bf16(a[m], b3[n], accu[m][n], 0, 0, 0);
                }
        }
        __syncthreads();
    }

#pragma unroll
    for (int m = 0; m < 4; ++m)
#pragma unroll
        for (int n = 0; n < 2; ++n)
#pragma unroll
            for (int r = 0; r < 4; ++r) {
                int lr = wr * 64 + m * 16 + (lane >> 4) * 4 + r;
                if (rbase + lr < cnt) {
                    float g = accg[m][n][r], u = accu[m][n][r];
                    float s = g / (1.f + __expf(-g));
                    int row = obase + rbase + lr;
                    int col = fbase + wc * 32 + n * 16 + (lane & 15);
                    int scol = col ^ ((row & 7) << 3);
                    act[(size_t)row * FF + scol] = f2bf(s * u);
                }
            }
}

// ---------------- GEMM2: y[z] = act @ w2^T ----------------
// NEW: BM=128, BN=128, 256 thr / 4 waves (2x2), wave-tile 64x64 (0.5 reads/MFMA),
// stride-64 XOR swizzle, split-K=ks.
__global__ __launch_bounds__(256, 4) void k_gemm2(
    const unsigned short* __restrict__ act, const float* __restrict__ w2,
    const int* __restrict__ counts, const int* __restrict__ offsets,
    const int* __restrict__ tle, const int* __restrict__ tlm,
    const int* __restrict__ tilecnt, float* __restrict__ y, int ks)
{
    int by = blockIdx.y;
    if (by >= tilecnt[1]) return;
    int e = tle[by];
    int rbase = tlm[by] * 128;
    int cnt = counts[e], obase = offsets[e];
    int hbase = blockIdx.x * 128;
    int z = blockIdx.z;
    const int KTOT = FF / 64;                  // 56
    int per = (KTOT + ks - 1) / ks;
    int kt0 = z * per;
    int ktn = (KTOT < kt0 + per ? KTOT : kt0 + per) - kt0;
    int kb0 = kt0 * 64;

    __shared__ __align__(16) unsigned short lA[128 * 64];   // 16 KB
    __shared__ __align__(16) unsigned short lB[128 * 64];   // 16 KB

    int tid = threadIdx.x;
    const int ra0 = tid >> 3, ca = (tid & 7) * 8;      // A: 32 rows/round, 4 rounds
    const unsigned short* pa[4];
#pragma unroll
    for (int i = 0; i < 4; ++i) {
        int r = obase + rbase + ra0 + 32 * i;
        if (r > 4095) r = 4095;
        pa[i] = act + (size_t)r * FF + kb0 + ca;       // act pre-swizzled; linear copy
    }
    int hr = tid >> 1, kh = tid & 1;                   // B: 128 H-rows, 32 f32 each half
    const float* pb = w2 + ((size_t)e * HID + hbase + hr) * FF + kb0 + kh * 32;
    int wba[4];
#pragma unroll
    for (int g = 0; g < 4; ++g)
        wba[g] = hr * 64 + ((kh * 32 + g * 8) ^ ((hr & 7) << 3));

    int lane = tid & 63, wv = tid >> 6, wr = wv >> 1, wc = wv & 1;
    int klane = (lane >> 4) * 8;
    int swzA = (((obase & 7) + (lane & 7)) & 7) << 3;
    int swzB = (lane & 7) << 3;
    f32x4 acc[4][4];
#pragma unroll
    for (int m = 0; m < 4; ++m)
#pragma unroll
        for (int n = 0; n < 4; ++n) acc[m][n] = (f32x4){0.f, 0.f, 0.f, 0.f};

    u16x8 ra[4]; float4 rw[8];
#pragma unroll
    for (int i = 0; i < 4; ++i) ra[i] = *(const u16x8*)(pa[i]);
#pragma unroll
    for (int j = 0; j < 8; ++j) rw[j] = *(const float4*)(pb + 4 * j);

    for (int kt = 0; kt < ktn; ++kt) {
#pragma unroll
        for (int i = 0; i < 4; ++i)
            *(u16x8*)(lA + (ra0 + 32 * i) * 64 + ca) = ra[i];
#pragma unroll
        for (int g = 0; g < 4; ++g) {
            uint4 q;
            q.x = cvtpk(rw[2 * g].x, rw[2 * g].y);
            q.y = cvtpk(rw[2 * g].z, rw[2 * g].w);
            q.z = cvtpk(rw[2 * g + 1].x, rw[2 * g + 1].y);
            q.w = cvtpk(rw[2 * g + 1].z, rw[2 * g + 1].w);
            *(uint4*)(lB + wba[g]) = q;
        }
        __syncthreads();
        if (kt < ktn - 1) {
            int kof = (kt + 1) * 64;
#pragma unroll
            for (int i = 0; i < 4; ++i) ra[i] = *(const u16x8*)(pa[i] + kof);
#pragma unroll
            for (int j = 0; j < 8; ++j) rw[j] = *(const float4*)(pb + kof + 4 * j);
        }
#pragma unroll
        for (int kk = 0; kk < 64; kk += 32) {
            int kc = kk + klane;
            int kA = kc ^ swzA, kB = kc ^ swzB;
            bf16x8 a[4], b[4];
#pragma unroll
            for (int m = 0; m < 4; ++m)
                a[m] = *(const bf16x8*)(lA + (wr * 64 + m * 16 + (lane & 15)) * 64 + kA);
#pragma unroll
            for (int n = 0; n < 4; ++n)
                b[n] = *(const bf16x8*)(lB + (wc * 64 + n * 16 + (lane & 15)) * 64 + kB);
#pragma unroll
            for (int m = 0; m < 4; ++m)
#pragma unroll
                for (int n = 0; n < 4; ++n)
                    acc[m][n] = __builtin_amdgcn_mfma_f32_16x16x32_bf16(a[m], b[n], acc[m][n], 0, 0, 0);
        }
        __syncthreads();
    }

    float* yz = y + (size_t)z * Y_STRIDE;
#pragma unroll
    for (int m = 0; m < 4; ++m)
#pragma unroll
        for (int n = 0; n < 4; ++n)
#pragma unroll
            for (int r = 0; r < 4; ++r) {
                int lr = wr * 64 + m * 16 + (lane >> 4) * 4 + r;
                if (rbase + lr < cnt) {
                    int col = hbase + wc * 64 + n * 16 + (lane & 15);
                    yz[(size_t)(obase + rbase + lr) * HID + col] = acc[m][n][r];
                }
            }
}

// ---------------- combine (split-K = ks) ----------------
__global__ void k_combine(const float* __restrict__ y, const int* __restrict__ slotrow,
                          const float* __restrict__ topkw, float* __restrict__ out, int ks) {
    int j = blockIdx.x * blockDim.x + threadIdx.x;
    int t = j >> 8, c = j & 255;
    int r0 = slotrow[2 * t], r1 = slotrow[2 * t + 1];
    float w0 = topkw[2 * t], w1 = topkw[2 * t + 1];
    float4 a = {0.f, 0.f, 0.f, 0.f}, b = {0.f, 0.f, 0.f, 0.f};
    for (int z = 0; z < ks; ++z) {
        const float4* yz = (const float4*)(y + (size_t)z * Y_STRIDE);
        float4 av = yz[(size_t)r0 * 256 + c];
        float4 bv = yz[(size_t)r1 * 256 + c];
        a.x += av.x; a.y += av.y; a.z += av.z; a.w += av.w;
        b.x += bv.x; b.y += bv.y; b.z += bv.z; b.w += bv.w;
    }
    float4 o;
    o.x = w0 * a.x + w1 * b.x;
    o.y = w0 * a.y + w1 * b.y;
    o.z = w0 * a.z + w1 * b.z;
    o.w = w0 * a.w + w1 * b.w;
    ((float4*)out)[j] = o;
}

extern "C" void kernel_launch(void* const* d_in, const int* in_sizes, int n_in,
                              void* d_out, int out_size, void* d_ws, size_t ws_size,
                              hipStream_t stream) {
    const float* x  = (const float*)d_in[0];
    const float* gw = (const float*)d_in[1];
    const float* w1 = (const float*)d_in[2];
    const float* w3 = (const float*)d_in[3];
    const float* w2 = (const float*)d_in[4];
    float* out = (float*)d_out;

    char* ws = (char*)d_ws;
    int*   counts   = (int*)(ws + WS_COUNTS);
    int*   offsets  = (int*)(ws + WS_OFFSETS);
    int*   tilecnt  = (int*)(ws + WS_TILECNT);
    int*   tl1e     = (int*)(ws + WS_TLE1);
    int*   tl1m     = (int*)(ws + WS_TLM1);
    int*   tl2e     = (int*)(ws + WS_TLE2);
    int*   tl2m     = (int*)(ws + WS_TLM2);
    int*   topki    = (int*)(ws + WS_TOPKI);
    float* topkw    = (float*)(ws + WS_TOPKW);
    int*   slotpos  = (int*)(ws + WS_SLOTPOS);
    int*   slotrow  = (int*)(ws + WS_SLOTROW);
    int*   routetok = (int*)(ws + WS_ROUTETOK);
    unsigned short* xg   = (unsigned short*)(ws + WS_XG);
    unsigned short* actb = (unsigned short*)(ws + WS_ACT);
    float* yb = (float*)(ws + WS_Y);

    size_t ybytes = (size_t)Y_STRIDE * 4;
    int ks = (ws_size >= (size_t)WS_Y + 4 * ybytes) ? 4 : 2;

    hipMemsetAsync(counts, 0, 64, stream);
    k_router<<<T_TOK / 4, 256, 0, stream>>>(x, gw, counts, topki, topkw, slotpos);
    k_prefix<<<1, 64, 0, stream>>>(counts, offsets, tl1e, tl1m, tl2e, tl2m, tilecnt);
    k_fill<<<16, 256, 0, stream>>>(topki, slotpos, offsets, routetok, slotrow);
    k_gather<<<4096, 256, 0, stream>>>(x, routetok, xg);
    k_gemm1<<<dim3(FF / 64, GRIDY1, 1), 512, 0, stream>>>(xg, w1, w3, counts, offsets, tl1e, tl1m, tilecnt, actb);
    k_gemm2<<<dim3(HID / 128, GRIDY2, ks), 256, 0, stream>>>(actb, w2, counts, offsets, tl2e, tl2m, tilecnt, yb, ks);
    k_combine<<<2048, 256, 0, stream>>>(yb, slotrow, topkw, out, ks);
}

// Round 11
// 264.151 us; speedup vs baseline: 1.4806x; 1.4806x over previous
//
#include <hip/hip_runtime.h>
#include <hip/hip_bf16.h>

// Problem constants
#define T_TOK 2048
#define HID   1024
#define FF    3584
#define NE    8
#define TOPK  2
#define GRIDY 24          // >= max tiles at BM=256: 16 + 7

typedef __bf16 bf16x8 __attribute__((ext_vector_type(8)));
typedef float  f32x4  __attribute__((ext_vector_type(4)));
typedef unsigned short u16x8 __attribute__((ext_vector_type(8)));

// ---- workspace layout (bytes) ----
#define WS_COUNTS   0u
#define WS_OFFSETS  64u
#define WS_TILECNT  128u
#define WS_TLE      256u
#define WS_TLM      512u
#define WS_TOPKI    4096u
#define WS_TOPKW    20480u
#define WS_SLOTPOS  36864u
#define WS_SLOTROW  53248u
#define WS_ROUTETOK 69632u
#define WS_XG       131072u                           // ushort[4096*1024] (8 MB), swizzled
#define WS_ACT      (WS_XG + 4096u*1024u*2u)          // ushort[4096*3584] (29.4 MB), swizzled
#define WS_Y        (WS_ACT + 4096u*3584u*2u)         // float[ks*4096*1024]
#define Y_STRIDE    (4096u*1024u)

static __device__ __forceinline__ unsigned short f2bf(float f) {
    unsigned int u = __builtin_bit_cast(unsigned int, f);
    u += 0x7FFFu + ((u >> 16) & 1u);
    return (unsigned short)(u >> 16);
}
static __device__ __forceinline__ unsigned int cvtpk(float lo, float hi) {
    unsigned int r;
    asm("v_cvt_pk_bf16_f32 %0, %1, %2" : "=v"(r) : "v"(lo), "v"(hi));
    return r;
}

// ---------------- router ----------------
__global__ __launch_bounds__(256) void k_router(
    const float* __restrict__ x, const float* __restrict__ gw,
    int* __restrict__ counts, int* __restrict__ topki,
    float* __restrict__ topkw, int* __restrict__ slotpos)
{
    int t = blockIdx.x * 4 + (threadIdx.x >> 6);
    int l = threadIdx.x & 63;
    const float* xr = x + (size_t)t * HID;
    float acc[NE];
#pragma unroll
    for (int e = 0; e < NE; ++e) acc[e] = 0.f;
#pragma unroll
    for (int i = 0; i < 4; ++i) {
        int h = l * 4 + i * 256;
        float4 xv = *(const float4*)(xr + h);
#pragma unroll
        for (int e = 0; e < NE; ++e) {
            float4 g = *(const float4*)(gw + e * HID + h);
            acc[e] += xv.x * g.x + xv.y * g.y + xv.z * g.z + xv.w * g.w;
        }
    }
#pragma unroll
    for (int e = 0; e < NE; ++e) {
#pragma unroll
        for (int off = 32; off; off >>= 1) acc[e] += __shfl_xor(acc[e], off);
    }
    if (l == 0) {
        float best = -1e30f, second = -1e30f;
        int bi = 0, si = 0;
#pragma unroll
        for (int e = 0; e < NE; ++e) {
            float v = acc[e];
            if (v > best) { second = best; si = bi; best = v; bi = e; }
            else if (v > second) { second = v; si = e; }
        }
        float w0 = 1.f / (1.f + __expf(second - best));
        float w1 = 1.f - w0;
        topki[2 * t] = bi;  topki[2 * t + 1] = si;
        topkw[2 * t] = w0;  topkw[2 * t + 1] = w1;
        slotpos[2 * t]     = atomicAdd(&counts[bi], 1);
        slotpos[2 * t + 1] = atomicAdd(&counts[si], 1);
    }
}

// ---------------- prefix + tile list (BM=256, shared by both GEMMs) ----------------
__global__ void k_prefix(const int* __restrict__ counts, int* __restrict__ offsets,
                         int* __restrict__ tle, int* __restrict__ tlm,
                         int* __restrict__ tilecnt) {
    if (threadIdx.x == 0) {
        int o = 0;
#pragma unroll
        for (int e = 0; e < NE; ++e) { offsets[e] = o; o += counts[e]; }
        int n = 0;
        for (int e = 0; e < NE; ++e) {
            int t = (counts[e] + 255) >> 8;
            for (int i = 0; i < t; ++i) { tle[n] = e; tlm[n] = i; ++n; }
        }
        tilecnt[0] = n;
    }
}

// ---------------- fill routing ----------------
__global__ void k_fill(const int* __restrict__ topki, const int* __restrict__ slotpos,
                       const int* __restrict__ offsets, int* __restrict__ routetok,
                       int* __restrict__ slotrow) {
    int j = blockIdx.x * blockDim.x + threadIdx.x;
    if (j >= T_TOK * TOPK) return;
    int e = topki[j];
    int row = offsets[e] + slotpos[j];
    routetok[row] = j >> 1;
    slotrow[j] = row;
}

// ---------------- gather + convert + swizzle (keyed on global slot row) ----------------
__global__ void k_gather(const float* __restrict__ x, const int* __restrict__ routetok,
                         unsigned short* __restrict__ xg) {
    int j = blockIdx.x * blockDim.x + threadIdx.x;
    int r = j >> 8;
    int c = (j & 255) * 4;
    int tok = routetok[r];
    float4 v = *(const float4*)(x + (size_t)tok * HID + c);
    ushort4 o;
    o.x = f2bf(v.x); o.y = f2bf(v.y); o.z = f2bf(v.z); o.w = f2bf(v.w);
    int sc = c ^ ((r & 7) << 3);
    *(ushort4*)(xg + (size_t)r * HID + sc) = o;
}

// ---------------- GEMM1: act = silu(Xg@w1^T) * (Xg@w3^T) ----------------
// (identical to R9) 512 thr / 8 waves, BM=256, BN=64 (x2), BK=64, stride-64 XOR swizzle.
__global__ __launch_bounds__(512, 4) void k_gemm1(
    const unsigned short* __restrict__ xg, const float* __restrict__ w1,
    const float* __restrict__ w3, const int* __restrict__ counts,
    const int* __restrict__ offsets, const int* __restrict__ tle,
    const int* __restrict__ tlm, const int* __restrict__ tilecnt,
    unsigned short* __restrict__ act)
{
    int by = blockIdx.y;
    if (by >= tilecnt[0]) return;
    int e = tle[by];
    int rbase = tlm[by] * 256;
    int cnt = counts[e], obase = offsets[e];
    int fbase = blockIdx.x * 64;

    __shared__ __align__(16) unsigned short lA[256 * 64];   // 32 KB
    __shared__ __align__(16) unsigned short lB1[64 * 64];   // 8 KB
    __shared__ __align__(16) unsigned short lB3[64 * 64];   // 8 KB

    int tid = threadIdx.x;
    const int ra0 = tid >> 3, ca = (tid & 7) * 8;
    const int rb0 = tid >> 4, cb = (tid & 15) * 4;
    const unsigned short* pa[4];
#pragma unroll
    for (int i = 0; i < 4; ++i) {
        int r = obase + rbase + ra0 + 64 * i;
        if (r > 4095) r = 4095;
        pa[i] = xg + (size_t)r * HID + ca;
    }
    const float* w1e = w1 + ((size_t)e * FF + fbase) * HID;
    const float* w3e = w3 + ((size_t)e * FF + fbase) * HID;
    const float* pb1[2];
    const float* pb3[2];
    int wba[2];
#pragma unroll
    for (int i = 0; i < 2; ++i) {
        int row = rb0 + 32 * i;
        pb1[i] = w1e + (size_t)row * HID + cb;
        pb3[i] = w3e + (size_t)row * HID + cb;
        wba[i] = row * 64 + (cb ^ ((row & 7) << 3));
    }

    int lane = tid & 63, wv = tid >> 6, wr = wv >> 1, wc = wv & 1;
    int klane = (lane >> 4) * 8;
    int swzA = (((obase & 7) + (lane & 7)) & 7) << 3;
    int swzB = (lane & 7) << 3;
    f32x4 accg[4][2], accu[4][2];
#pragma unroll
    for (int m = 0; m < 4; ++m)
#pragma unroll
        for (int n = 0; n < 2; ++n) {
            accg[m][n] = (f32x4){0.f, 0.f, 0.f, 0.f};
            accu[m][n] = (f32x4){0.f, 0.f, 0.f, 0.f};
        }

    u16x8 ra[4]; float4 r1[2], r3[2];
#pragma unroll
    for (int i = 0; i < 4; ++i) ra[i] = *(const u16x8*)(pa[i]);
#pragma unroll
    for (int i = 0; i < 2; ++i) { r1[i] = *(const float4*)(pb1[i]); r3[i] = *(const float4*)(pb3[i]); }

    for (int kt = 0; kt < HID / 64; ++kt) {
#pragma unroll
        for (int i = 0; i < 4; ++i)
            *(u16x8*)(lA + (ra0 + 64 * i) * 64 + ca) = ra[i];
#pragma unroll
        for (int i = 0; i < 2; ++i) {
            uint2 p;
            p.x = cvtpk(r1[i].x, r1[i].y); p.y = cvtpk(r1[i].z, r1[i].w);
            *(uint2*)(lB1 + wba[i]) = p;
            p.x = cvtpk(r3[i].x, r3[i].y); p.y = cvtpk(r3[i].z, r3[i].w);
            *(uint2*)(lB3 + wba[i]) = p;
        }
        __syncthreads();
        if (kt < HID / 64 - 1) {
            int kof = (kt + 1) * 64;
#pragma unroll
            for (int i = 0; i < 4; ++i) ra[i] = *(const u16x8*)(pa[i] + kof);
#pragma unroll
            for (int i = 0; i < 2; ++i) {
                r1[i] = *(const float4*)(pb1[i] + kof);
                r3[i] = *(const float4*)(pb3[i] + kof);
            }
        }
#pragma unroll
        for (int kk = 0; kk < 64; kk += 32) {
            int kc = kk + klane;
            int kA = kc ^ swzA, kB = kc ^ swzB;
            bf16x8 a[4], b1[2], b3[2];
#pragma unroll
            for (int m = 0; m < 4; ++m)
                a[m] = *(const bf16x8*)(lA + (wr * 64 + m * 16 + (lane & 15)) * 64 + kA);
#pragma unroll
            for (int n = 0; n < 2; ++n) {
                b1[n] = *(const bf16x8*)(lB1 + (wc * 32 + n * 16 + (lane & 15)) * 64 + kB);
                b3[n] = *(const bf16x8*)(lB3 + (wc * 32 + n * 16 + (lane & 15)) * 64 + kB);
            }
#pragma unroll
            for (int m = 0; m < 4; ++m)
#pragma unroll
                for (int n = 0; n < 2; ++n) {
                    accg[m][n] = __builtin_amdgcn_mfma_f32_16x16x32_bf16(a[m], b1[n], accg[m][n], 0, 0, 0);
                    accu[m][n] = __builtin_amdgcn_mfma_f32_16x16x32_bf16(a[m], b3[n], accu[m][n], 0, 0, 0);
                }
        }
        __syncthreads();
    }

#pragma unroll
    for (int m = 0; m < 4; ++m)
#pragma unroll
        for (int n = 0; n < 2; ++n)
#pragma unroll
            for (int r = 0; r < 4; ++r) {
                int lr = wr * 64 + m * 16 + (lane >> 4) * 4 + r;
                if (rbase + lr < cnt) {
                    float g = accg[m][n][r], u = accu[m][n][r];
                    float s = g / (1.f + __expf(-g));
                    int row = obase + rbase + lr;
                    int col = fbase + wc * 32 + n * 16 + (lane & 15);
                    int scol = col ^ ((row & 7) << 3);
                    act[(size_t)row * FF + scol] = f2bf(s * u);
                }
            }
}

// ---------------- GEMM2: y[z] = act @ w2^T ----------------
// BM=256, BN=128, 512 thr / 8 waves (4M x 2N), wave-tile 64x64, BK=64,
// stride-64 XOR swizzle, split-K=ks (K-contiguous slices), R9 2-phase skeleton.
__global__ __launch_bounds__(512, 4) void k_gemm2(
    const unsigned short* __restrict__ act, const float* __restrict__ w2,
    const int* __restrict__ counts, const int* __restrict__ offsets,
    const int* __restrict__ tle, const int* __restrict__ tlm,
    const int* __restrict__ tilecnt, float* __restrict__ y, int ks)
{
    int by = blockIdx.y;
    if (by >= tilecnt[0]) return;
    int e = tle[by];
    int rbase = tlm[by] * 256;
    int cnt = counts[e], obase = offsets[e];
    int hbase = blockIdx.x * 128;
    int z = blockIdx.z;
    const int KTOT = FF / 64;                  // 56
    int per = (KTOT + ks - 1) / ks;
    int kt0 = z * per;
    int ktn = (KTOT < kt0 + per ? KTOT : kt0 + per) - kt0;
    int kb0 = kt0 * 64;

    __shared__ __align__(16) unsigned short lA[256 * 64];   // 32 KB
    __shared__ __align__(16) unsigned short lB[128 * 64];   // 16 KB

    int tid = threadIdx.x;
    const int ra0 = tid >> 3, ca = (tid & 7) * 8;      // A: 64 rows/round, 4 rounds
    const unsigned short* pa[4];
#pragma unroll
    for (int i = 0; i < 4; ++i) {
        int r = obase + rbase + ra0 + 64 * i;
        if (r > 4095) r = 4095;
        pa[i] = act + (size_t)r * FF + kb0 + ca;       // act pre-swizzled; linear copy
    }
    // B: 128 H-rows x 64 f32; thread -> row tid>>2, 16 f32 at (tid&3)*16
    int hr = tid >> 2, cbf = (tid & 3) * 16;
    const float* pb = w2 + ((size_t)e * HID + hbase + hr) * FF + kb0 + cbf;
    int wbb[2];
#pragma unroll
    for (int g = 0; g < 2; ++g)
        wbb[g] = hr * 64 + ((cbf + g * 8) ^ ((hr & 7) << 3));

    int lane = tid & 63, wv = tid >> 6;
    int wr = wv & 3, wc = wv >> 2;                     // 4M x 2N
    int klane = (lane >> 4) * 8;
    int swzA = (((obase & 7) + (lane & 7)) & 7) << 3;
    int swzB = (lane & 7) << 3;
    f32x4 acc[4][4];
#pragma unroll
    for (int m = 0; m < 4; ++m)
#pragma unroll
        for (int n = 0; n < 4; ++n) acc[m][n] = (f32x4){0.f, 0.f, 0.f, 0.f};

    u16x8 ra[4]; float4 rw[4];
#pragma unroll
    for (int i = 0; i < 4; ++i) ra[i] = *(const u16x8*)(pa[i]);
#pragma unroll
    for (int j = 0; j < 4; ++j) rw[j] = *(const float4*)(pb + 4 * j);

    for (int kt = 0; kt < ktn; ++kt) {
#pragma unroll
        for (int i = 0; i < 4; ++i)
            *(u16x8*)(lA + (ra0 + 64 * i) * 64 + ca) = ra[i];
#pragma unroll
        for (int g = 0; g < 2; ++g) {
            uint4 q;
            q.x = cvtpk(rw[2 * g].x, rw[2 * g].y);
            q.y = cvtpk(rw[2 * g].z, rw[2 * g].w);
            q.z = cvtpk(rw[2 * g + 1].x, rw[2 * g + 1].y);
            q.w = cvtpk(rw[2 * g + 1].z, rw[2 * g + 1].w);
            *(uint4*)(lB + wbb[g]) = q;
        }
        __syncthreads();
        if (kt < ktn - 1) {
            int kof = (kt + 1) * 64;
#pragma unroll
            for (int i = 0; i < 4; ++i) ra[i] = *(const u16x8*)(pa[i] + kof);
#pragma unroll
            for (int j = 0; j < 4; ++j) rw[j] = *(const float4*)(pb + kof + 4 * j);
        }
#pragma unroll
        for (int kk = 0; kk < 64; kk += 32) {
            int kc = kk + klane;
            int kA = kc ^ swzA, kB = kc ^ swzB;
            bf16x8 a[4], b[4];
#pragma unroll
            for (int m = 0; m < 4; ++m)
                a[m] = *(const bf16x8*)(lA + (wr * 64 + m * 16 + (lane & 15)) * 64 + kA);
#pragma unroll
            for (int n = 0; n < 4; ++n)
                b[n] = *(const bf16x8*)(lB + (wc * 64 + n * 16 + (lane & 15)) * 64 + kB);
#pragma unroll
            for (int m = 0; m < 4; ++m)
#pragma unroll
                for (int n = 0; n < 4; ++n)
                    acc[m][n] = __builtin_amdgcn_mfma_f32_16x16x32_bf16(a[m], b[n], acc[m][n], 0, 0, 0);
        }
        __syncthreads();
    }

    float* yz = y + (size_t)z * Y_STRIDE;
#pragma unroll
    for (int m = 0; m < 4; ++m)
#pragma unroll
        for (int n = 0; n < 4; ++n)
#pragma unroll
            for (int r = 0; r < 4; ++r) {
                int lr = wr * 64 + m * 16 + (lane >> 4) * 4 + r;
                if (rbase + lr < cnt) {
                    int col = hbase + wc * 64 + n * 16 + (lane & 15);
                    yz[(size_t)(obase + rbase + lr) * HID + col] = acc[m][n][r];
                }
            }
}

// ---------------- combine (split-K = ks, fixed order) ----------------
__global__ void k_combine(const float* __restrict__ y, const int* __restrict__ slotrow,
                          const float* __restrict__ topkw, float* __restrict__ out, int ks) {
    int j = blockIdx.x * blockDim.x + threadIdx.x;
    int t = j >> 8, c = j & 255;
    int r0 = slotrow[2 * t], r1 = slotrow[2 * t + 1];
    float w0 = topkw[2 * t], w1 = topkw[2 * t + 1];
    float4 a = {0.f, 0.f, 0.f, 0.f}, b = {0.f, 0.f, 0.f, 0.f};
    for (int z = 0; z < ks; ++z) {
        const float4* yz = (const float4*)(y + (size_t)z * Y_STRIDE);
        float4 av = yz[(size_t)r0 * 256 + c];
        float4 bv = yz[(size_t)r1 * 256 + c];
        a.x += av.x; a.y += av.y; a.z += av.z; a.w += av.w;
        b.x += bv.x; b.y += bv.y; b.z += bv.z; b.w += bv.w;
    }
    float4 o;
    o.x = w0 * a.x + w1 * b.x;
    o.y = w0 * a.y + w1 * b.y;
    o.z = w0 * a.z + w1 * b.z;
    o.w = w0 * a.w + w1 * b.w;
    ((float4*)out)[j] = o;
}

extern "C" void kernel_launch(void* const* d_in, const int* in_sizes, int n_in,
                              void* d_out, int out_size, void* d_ws, size_t ws_size,
                              hipStream_t stream) {
    const float* x  = (const float*)d_in[0];
    const float* gw = (const float*)d_in[1];
    const float* w1 = (const float*)d_in[2];
    const float* w3 = (const float*)d_in[3];
    const float* w2 = (const float*)d_in[4];
    float* out = (float*)d_out;

    char* ws = (char*)d_ws;
    int*   counts   = (int*)(ws + WS_COUNTS);
    int*   offsets  = (int*)(ws + WS_OFFSETS);
    int*   tilecnt  = (int*)(ws + WS_TILECNT);
    int*   tle      = (int*)(ws + WS_TLE);
    int*   tlm      = (int*)(ws + WS_TLM);
    int*   topki    = (int*)(ws + WS_TOPKI);
    float* topkw    = (float*)(ws + WS_TOPKW);
    int*   slotpos  = (int*)(ws + WS_SLOTPOS);
    int*   slotrow  = (int*)(ws + WS_SLOTROW);
    int*   routetok = (int*)(ws + WS_ROUTETOK);
    unsigned short* xg   = (unsigned short*)(ws + WS_XG);
    unsigned short* actb = (unsigned short*)(ws + WS_ACT);
    float* yb = (float*)(ws + WS_Y);

    size_t ybytes = (size_t)Y_STRIDE * 4;
    int ks = (ws_size >= (size_t)WS_Y + 3 * ybytes) ? 3 : 2;

    hipMemsetAsync(counts, 0, 64, stream);
    k_router<<<T_TOK / 4, 256, 0, stream>>>(x, gw, counts, topki, topkw, slotpos);
    k_prefix<<<1, 64, 0, stream>>>(counts, offsets, tle, tlm, tilecnt);
    k_fill<<<16, 256, 0, stream>>>(topki, slotpos, offsets, routetok, slotrow);
    k_gather<<<4096, 256, 0, stream>>>(x, routetok, xg);
    k_gemm1<<<dim3(FF / 64, GRIDY, 1), 512, 0, stream>>>(xg, w1, w3, counts, offsets, tle, tlm, tilecnt, actb);
    k_gemm2<<<dim3(HID / 128, GRIDY, ks), 512, 0, stream>>>(actb, w2, counts, offsets, tle, tlm, tilecnt, yb, ks);
    k_combine<<<2048, 256, 0, stream>>>(yb, slotrow, topkw, out, ks);
}